// Round 2
// baseline (367.820 us; speedup 1.0000x reference)
//
#include <hip/hip_runtime.h>
#include <cstdint>
#include <cstddef>

// SSM layer: y = scan(x @ B^T) @ C^T + D * x
// x: (8,4096,1024) f32; A: (256,); B: (256,1024); C: (1024,256); D: (1024,)
// M = 32768 flattened rows (row = b*4096 + t; 4096 % 64 == 0 so a 64-row
// chunk never crosses a batch boundary).
//
// Pipeline: gemm_bx (f16 out) -> scan_E -> scan_prefix -> scan_apply (in
// place f16) -> gemm_y (fused D*x epilogue).

typedef __attribute__((ext_vector_type(8))) _Float16 half8;
typedef __attribute__((ext_vector_type(4))) float f32x4;

__device__ inline half8 cvt8(float4 a, float4 b) {
  half8 h;
  h[0] = (_Float16)a.x; h[1] = (_Float16)a.y;
  h[2] = (_Float16)a.z; h[3] = (_Float16)a.w;
  h[4] = (_Float16)b.x; h[5] = (_Float16)b.y;
  h[6] = (_Float16)b.z; h[7] = (_Float16)b.w;
  return h;
}

// ---------------------------------------------------------------------------
// GEMM1: Bx[M,256] = x[M,1024] * B[256,1024]^T, output f16.
// BM=64, BN=256 (full N -> x fetched exactly once), BK=32.
// 256 threads = 4 waves; wave w owns rows 0..63 x cols w*64..w*64+63.
// Double-buffered LDS, one barrier per K-iter.
// ---------------------------------------------------------------------------
__global__ __launch_bounds__(256) void gemm_bx(
    const float* __restrict__ x, const float* __restrict__ Bp,
    _Float16* __restrict__ Bxh)
{
  constexpr int LDT = 40;   // padded stride (halves)
  __shared__ __align__(16) _Float16 lA[2][64 * LDT];
  __shared__ __align__(16) _Float16 lB[2][256 * LDT];

  const int tid  = threadIdx.x;
  const int lane = tid & 63;
  const int wave = tid >> 6;
  const int wn   = wave * 64;
  const int quad = lane >> 4;
  const int l16  = lane & 15;
  const long blockM = (long)blockIdx.x * 64;

  // A staging: 64x32 = 256 chunks of 8 -> 1 chunk/thread
  const int arow = tid >> 2, akc = (tid & 3) * 8;
  const float* gA = x + (blockM + arow) * 1024 + akc;
  // B staging: 256x32 = 1024 chunks -> 4 chunks/thread
  int brow[4], bkc[4];
  const float* gB[4];
  #pragma unroll
  for (int i = 0; i < 4; i++) {
    const int ch = tid + i * 256;
    brow[i] = ch >> 2; bkc[i] = (ch & 3) * 8;
    gB[i] = Bp + brow[i] * 1024 + bkc[i];
  }

  float4 ra0, ra1, rb0[4], rb1[4];
  // prologue: load k=0 tile
  ra0 = *(const float4*)gA; ra1 = *(const float4*)(gA + 4);
  #pragma unroll
  for (int i = 0; i < 4; i++) {
    rb0[i] = *(const float4*)gB[i]; rb1[i] = *(const float4*)(gB[i] + 4);
  }
  *(half8*)&lA[0][arow * LDT + akc] = cvt8(ra0, ra1);
  #pragma unroll
  for (int i = 0; i < 4; i++)
    *(half8*)&lB[0][brow[i] * LDT + bkc[i]] = cvt8(rb0[i], rb1[i]);
  __syncthreads();

  f32x4 acc[4][4];
  #pragma unroll
  for (int i = 0; i < 4; i++)
    #pragma unroll
    for (int j = 0; j < 4; j++) acc[i][j] = (f32x4){0.f, 0.f, 0.f, 0.f};

  for (int it = 0; it < 32; ++it) {
    const int cur = it & 1;
    if (it < 31) {   // prefetch next tile into registers
      const int k = (it + 1) * 32;
      ra0 = *(const float4*)(gA + k); ra1 = *(const float4*)(gA + k + 4);
      #pragma unroll
      for (int i = 0; i < 4; i++) {
        rb0[i] = *(const float4*)(gB[i] + k);
        rb1[i] = *(const float4*)(gB[i] + k + 4);
      }
    }
    half8 af[4], bf[4];
    #pragma unroll
    for (int mt = 0; mt < 4; mt++)
      af[mt] = *(const half8*)&lA[cur][(mt * 16 + l16) * LDT + quad * 8];
    #pragma unroll
    for (int nt = 0; nt < 4; nt++)
      bf[nt] = *(const half8*)&lB[cur][(wn + nt * 16 + l16) * LDT + quad * 8];
    #pragma unroll
    for (int mt = 0; mt < 4; mt++)
      #pragma unroll
      for (int nt = 0; nt < 4; nt++)
        acc[mt][nt] = __builtin_amdgcn_mfma_f32_16x16x32_f16(
            af[mt], bf[nt], acc[mt][nt], 0, 0, 0);
    if (it < 31) {   // store prefetched tile to alternate buffer
      *(half8*)&lA[cur ^ 1][arow * LDT + akc] = cvt8(ra0, ra1);
      #pragma unroll
      for (int i = 0; i < 4; i++)
        *(half8*)&lB[cur ^ 1][brow[i] * LDT + bkc[i]] = cvt8(rb0[i], rb1[i]);
    }
    __syncthreads();
  }

  // epilogue: C/D layout col=lane&15, row=quad*4+reg
  #pragma unroll
  for (int mt = 0; mt < 4; mt++)
    #pragma unroll
    for (int nt = 0; nt < 4; nt++) {
      const int col = wn + nt * 16 + l16;
      #pragma unroll
      for (int r = 0; r < 4; r++) {
        const long row = blockM + mt * 16 + quad * 4 + r;
        Bxh[row * 256 + col] = (_Float16)acc[mt][nt][r];
      }
    }
}

// ---------------------------------------------------------------------------
// Scan, chunked: s=4096 -> 64 chunks of 64 per batch, chunk id bc = row>>6.
// ---------------------------------------------------------------------------

// Pass 1: chunk-end local sums only (no writeback).
__global__ __launch_bounds__(256) void scan_E(
    const _Float16* __restrict__ Bxh, const float* __restrict__ Ap,
    float* __restrict__ E)
{
  const int n  = threadIdx.x;
  const int bc = blockIdx.x;
  const float al = expf(-expf(Ap[n]));
  const size_t base = (size_t)bc * 64 * 256 + n;
  float h = 0.f;
  #pragma unroll 8
  for (int t = 0; t < 64; t++)
    h = fmaf(al, h, (float)Bxh[base + (size_t)t * 256]);
  E[(size_t)bc * 256 + n] = h;
}

// Pass 2: sequential carry prefix across 64 chunks per (b,n).
__global__ __launch_bounds__(256) void scan_prefix(
    const float* __restrict__ E, const float* __restrict__ Ap,
    float* __restrict__ carry)
{
  const int n = threadIdx.x;
  const int b = blockIdx.x;
  const float al = expf(-expf(Ap[n]));
  float aL = al;
  #pragma unroll
  for (int i = 0; i < 6; i++) aL *= aL;   // al^64
  float run = 0.f;
  for (int c = 0; c < 64; c++) {
    const size_t idx = ((size_t)b * 64 + c) * 256 + n;
    carry[idx] = run;                      // h at end of previous chunk
    run = fmaf(aL, run, E[idx]);
  }
}

// Pass 3: full scan with h(-1)=carry, in place (f16 -> f16, same indices).
__global__ __launch_bounds__(256) void scan_apply(
    _Float16* __restrict__ Bxh, const float* __restrict__ Ap,
    const float* __restrict__ carry)
{
  const int n  = threadIdx.x;
  const int bc = blockIdx.x;
  const float al = expf(-expf(Ap[n]));
  float h = carry[(size_t)bc * 256 + n];
  const size_t base = (size_t)bc * 64 * 256 + n;
  #pragma unroll 8
  for (int t = 0; t < 64; t++) {
    const size_t i = base + (size_t)t * 256;
    h = fmaf(al, h, (float)Bxh[i]);
    Bxh[i] = (_Float16)h;
  }
}

// ---------------------------------------------------------------------------
// GEMM2: y[M,1024] = hs[M,256](f16) * C[1024,256]^T + D*x.
// BM=128, BN=128, BK=32; 4 waves in 2x2 grid of 64x64 quadrants.
// Double-buffered; A-staging is a pure half8 copy.
// ---------------------------------------------------------------------------
__global__ __launch_bounds__(256) void gemm_y(
    const _Float16* __restrict__ hs, const float* __restrict__ Cp,
    const float* __restrict__ x, const float* __restrict__ Dp,
    float* __restrict__ y)
{
  constexpr int LDT = 40;
  __shared__ __align__(16) _Float16 lA[2][128 * LDT];
  __shared__ __align__(16) _Float16 lB[2][128 * LDT];

  const int tid  = threadIdx.x;
  const int lane = tid & 63;
  const int wave = tid >> 6;
  const int wm   = (wave & 1) * 64;
  const int wn   = (wave >> 1) * 64;
  const int quad = lane >> 4;
  const int l16  = lane & 15;
  const long blockM = (long)blockIdx.x * 128;
  const long blockN = (long)blockIdx.y * 128;

  // staging: 128x32 = 512 chunks of 8 -> 2 chunks/thread (A and B same split)
  int ar[2], ak[2];
  const _Float16* gA[2];
  const float* gB[2];
  #pragma unroll
  for (int i = 0; i < 2; i++) {
    const int ch = tid + i * 256;
    ar[i] = ch >> 2; ak[i] = (ch & 3) * 8;
    gA[i] = hs + (blockM + ar[i]) * 256 + ak[i];
    gB[i] = Cp + (blockN + ar[i]) * 256 + ak[i];
  }

  half8 ha[2]; float4 rb0[2], rb1[2];
  #pragma unroll
  for (int i = 0; i < 2; i++) {
    ha[i]  = *(const half8*)gA[i];
    rb0[i] = *(const float4*)gB[i];
    rb1[i] = *(const float4*)(gB[i] + 4);
  }
  #pragma unroll
  for (int i = 0; i < 2; i++) {
    *(half8*)&lA[0][ar[i] * LDT + ak[i]] = ha[i];
    *(half8*)&lB[0][ar[i] * LDT + ak[i]] = cvt8(rb0[i], rb1[i]);
  }
  __syncthreads();

  f32x4 acc[4][4];
  #pragma unroll
  for (int i = 0; i < 4; i++)
    #pragma unroll
    for (int j = 0; j < 4; j++) acc[i][j] = (f32x4){0.f, 0.f, 0.f, 0.f};

  for (int it = 0; it < 8; ++it) {
    const int cur = it & 1;
    if (it < 7) {
      const int k = (it + 1) * 32;
      #pragma unroll
      for (int i = 0; i < 2; i++) {
        ha[i]  = *(const half8*)(gA[i] + k);
        rb0[i] = *(const float4*)(gB[i] + k);
        rb1[i] = *(const float4*)(gB[i] + k + 4);
      }
    }
    half8 af[4], bf[4];
    #pragma unroll
    for (int mt = 0; mt < 4; mt++)
      af[mt] = *(const half8*)&lA[cur][(wm + mt * 16 + l16) * LDT + quad * 8];
    #pragma unroll
    for (int nt = 0; nt < 4; nt++)
      bf[nt] = *(const half8*)&lB[cur][(wn + nt * 16 + l16) * LDT + quad * 8];
    #pragma unroll
    for (int mt = 0; mt < 4; mt++)
      #pragma unroll
      for (int nt = 0; nt < 4; nt++)
        acc[mt][nt] = __builtin_amdgcn_mfma_f32_16x16x32_f16(
            af[mt], bf[nt], acc[mt][nt], 0, 0, 0);
    if (it < 7) {
      #pragma unroll
      for (int i = 0; i < 2; i++) {
        *(half8*)&lA[cur ^ 1][ar[i] * LDT + ak[i]] = ha[i];
        *(half8*)&lB[cur ^ 1][ar[i] * LDT + ak[i]] = cvt8(rb0[i], rb1[i]);
      }
    }
    __syncthreads();
  }

  // epilogue: y = acc + D[col] * x[row][col]
  #pragma unroll
  for (int mt = 0; mt < 4; mt++)
    #pragma unroll
    for (int nt = 0; nt < 4; nt++) {
      const long col = blockN + wn + nt * 16 + l16;
      const float dcol = Dp[col];
      #pragma unroll
      for (int r = 0; r < 4; r++) {
        const long row = blockM + wm + mt * 16 + quad * 4 + r;
        y[row * 1024 + col] = acc[mt][nt][r] + dcol * x[row * 1024 + col];
      }
    }
}

// ---------------------------------------------------------------------------
extern "C" void kernel_launch(void* const* d_in, const int* in_sizes, int n_in,
                              void* d_out, int out_size, void* d_ws, size_t ws_size,
                              hipStream_t stream) {
  const float* x  = (const float*)d_in[0];
  const float* Ap = (const float*)d_in[1];
  const float* Bp = (const float*)d_in[2];
  const float* Cp = (const float*)d_in[3];
  const float* Dp = (const float*)d_in[4];
  float* y = (float*)d_out;

  // workspace: Bxh (32768x256 f16, 16.8MB) | E (512x256 f32) | carry (512x256)
  _Float16* Bxh  = (_Float16*)d_ws;
  float*    E    = (float*)((char*)d_ws + (size_t)32768 * 256 * 2);
  float*    carry = E + (size_t)512 * 256;

  gemm_bx   <<<512, 256, 0, stream>>>(x, Bp, Bxh);
  scan_E    <<<512, 256, 0, stream>>>(Bxh, Ap, E);
  scan_prefix<<<8,  256, 0, stream>>>(E, Ap, carry);
  scan_apply<<<512, 256, 0, stream>>>(Bxh, Ap, carry);
  gemm_y<<<dim3(256, 8), 256, 0, stream>>>(Bxh, Cp, x, Dp, y);
}

// Round 3
// 348.586 us; speedup vs baseline: 1.0552x; 1.0552x over previous
//
#include <hip/hip_runtime.h>
#include <cstdint>
#include <cstddef>

// SSM layer: y = scan(x @ B^T) @ C^T + D * x
// x: (8,4096,1024) f32; A: (256,); B: (256,1024); C: (1024,256); D: (1024,)
// M = 32768 rows. Pipeline:
//   cvt (B,C -> f16) -> gemm_bx -> scan_E -> scan_prefix -> scan_apply -> gemm_y
// Design: operand-stationary 64KB LDS slabs (XOR bank swizzle, no pad so the
// full 64KB static budget is usable), barrier-free streaming of the big
// operands (x, hs) directly into MFMA fragments for deep MLP.

typedef __attribute__((ext_vector_type(8))) _Float16 half8;
typedef __attribute__((ext_vector_type(4))) float f32x4;

__device__ inline half8 cvt8(float4 a, float4 b) {
  half8 h;
  h[0] = (_Float16)a.x; h[1] = (_Float16)a.y;
  h[2] = (_Float16)a.z; h[3] = (_Float16)a.w;
  h[4] = (_Float16)b.x; h[5] = (_Float16)b.y;
  h[6] = (_Float16)b.z; h[7] = (_Float16)b.w;
  return h;
}

// ---------------------------------------------------------------------------
// Convert B (256x1024) and C (1024x256) to f16. 65536 threads x 8 elems.
// ---------------------------------------------------------------------------
__global__ __launch_bounds__(256) void cvt_bc(
    const float* __restrict__ Bp, const float* __restrict__ Cp,
    _Float16* __restrict__ Bh, _Float16* __restrict__ Ch)
{
  const int g = blockIdx.x * 256 + threadIdx.x;      // 0..65535
  const size_t off = (size_t)(g & 32767) * 8;
  const float* src = (g < 32768) ? (Bp + off) : (Cp + off);
  _Float16*    dst = (g < 32768) ? (Bh + off) : (Ch + off);
  float4 a = *(const float4*)src;
  float4 b = *(const float4*)(src + 4);
  *(half8*)dst = cvt8(a, b);
}

// ---------------------------------------------------------------------------
// GEMM1: Bx[M,256] = x[M,1024] * B[256,1024]^T  (f16 out)
// Block = 64 rows; wave w owns rows w*16..+15 x ALL 256 n.
// B-slab chunk (256n x 128k f16 = 64KB, XOR-swizzled) in LDS, refilled from
// L2 each K-chunk. A-fragments stream straight from global x (f32->f16 cvt
// in registers) -- x is read exactly once, 128B-per-row coalesced.
// ---------------------------------------------------------------------------
__global__ __launch_bounds__(256) void gemm_bx(
    const float* __restrict__ x, const _Float16* __restrict__ Bh,
    _Float16* __restrict__ Bxh)
{
  __shared__ _Float16 lb[256 * 128];   // 64KB, [n][k8p*8], k8p = k8 ^ (n&7)

  const int tid  = threadIdx.x;
  const int lane = tid & 63;
  const int wave = tid >> 6;
  const int quad = lane >> 4;
  const int l16  = lane & 15;
  const long blockM = (long)blockIdx.x * 64;
  const long arow = blockM + wave * 16 + l16;     // global A row for frags

  f32x4 acc[16];
  #pragma unroll
  for (int i = 0; i < 16; i++) acc[i] = (f32x4){0.f, 0.f, 0.f, 0.f};

  for (int kc = 0; kc < 8; kc++) {
    __syncthreads();   // previous chunk's readers done
    // fill B-slab: thread t = row n, 16 x 16B from L2-resident Bh
    {
      const int n = tid;
      const _Float16* src = Bh + (size_t)n * 1024 + kc * 128;
      #pragma unroll
      for (int j = 0; j < 16; j++) {
        half8 v = *(const half8*)(src + j * 8);
        const int k8p = j ^ (n & 7);
        *(half8*)&lb[n * 128 + k8p * 8] = v;
      }
    }
    // A-fragments for this chunk (4 ks), direct from x
    half8 af[4];
    #pragma unroll
    for (int ks = 0; ks < 4; ks++) {
      const float* ga = x + arow * 1024 + kc * 128 + ks * 32 + quad * 8;
      float4 a0 = *(const float4*)ga;
      float4 a1 = *(const float4*)(ga + 4);
      af[ks] = cvt8(a0, a1);
    }
    __syncthreads();
    #pragma unroll
    for (int ks = 0; ks < 4; ks++) {
      #pragma unroll
      for (int nt = 0; nt < 16; nt++) {
        const int n   = nt * 16 + l16;
        const int k8p = (ks * 4 + quad) ^ (n & 7);
        half8 bf = *(const half8*)&lb[n * 128 + k8p * 8];
        acc[nt] = __builtin_amdgcn_mfma_f32_16x16x32_f16(af[ks], bf, acc[nt], 0, 0, 0);
      }
    }
  }

  // epilogue: bounce through LDS to emit coalesced 16B f16 stores.
  __syncthreads();
  #pragma unroll
  for (int nt = 0; nt < 16; nt++)
    #pragma unroll
    for (int r = 0; r < 4; r++)
      lb[(wave * 16 + quad * 4 + r) * 256 + nt * 16 + l16] = (_Float16)acc[nt][r];
  __syncthreads();
  {
    const int row = tid >> 2, seg = tid & 3;       // 64 rows x 4 segs
    _Float16* dst = Bxh + (blockM + row) * 256 + seg * 64;
    const _Float16* srcl = &lb[row * 256 + seg * 64];
    #pragma unroll
    for (int j = 0; j < 8; j++)
      *(half8*)(dst + j * 8) = *(const half8*)(srcl + j * 8);
  }
}

// ---------------------------------------------------------------------------
// Scan (chunked): 64 chunks of 64 steps per batch; layout Bxh[row][n].
// ---------------------------------------------------------------------------
__global__ __launch_bounds__(256) void scan_E(
    const _Float16* __restrict__ Bxh, const float* __restrict__ Ap,
    float* __restrict__ E)
{
  const int n  = threadIdx.x;
  const int bc = blockIdx.x;
  const float al = expf(-expf(Ap[n]));
  const size_t base = (size_t)bc * 64 * 256 + n;
  float h = 0.f;
  #pragma unroll 8
  for (int t = 0; t < 64; t++)
    h = fmaf(al, h, (float)Bxh[base + (size_t)t * 256]);
  E[(size_t)bc * 256 + n] = h;
}

__global__ __launch_bounds__(256) void scan_prefix(
    const float* __restrict__ E, const float* __restrict__ Ap,
    float* __restrict__ carry)
{
  const int n = threadIdx.x;
  const int b = blockIdx.x;
  const float al = expf(-expf(Ap[n]));
  float aL = al;
  #pragma unroll
  for (int i = 0; i < 6; i++) aL *= aL;   // al^64
  float run = 0.f;
  for (int c = 0; c < 64; c++) {
    const size_t idx = ((size_t)b * 64 + c) * 256 + n;
    carry[idx] = run;
    run = fmaf(aL, run, E[idx]);
  }
}

__global__ __launch_bounds__(256) void scan_apply(
    _Float16* __restrict__ Bxh, const float* __restrict__ Ap,
    const float* __restrict__ carry)
{
  const int n  = threadIdx.x;
  const int bc = blockIdx.x;
  const float al = expf(-expf(Ap[n]));
  float h = carry[(size_t)bc * 256 + n];
  const size_t base = (size_t)bc * 64 * 256 + n;
  #pragma unroll 8
  for (int t = 0; t < 64; t++) {
    const size_t i = base + (size_t)t * 256;
    h = fmaf(al, h, (float)Bxh[i]);
    Bxh[i] = (_Float16)h;
  }
}

// ---------------------------------------------------------------------------
// GEMM2: y[M,1024] = hs[M,256] * C[1024,256]^T + D*x
// Block: n-slab = 128 cols (slab = blockIdx&7), 8 M-chunks of 64 rows
// (mgroup = blockIdx>>3). C-slab (128x256 f16 = 64KB, swizzled) loaded ONCE;
// M-loop is barrier-free: hs A-frags + x tiles stream direct from global.
// Blocks 8m..8m+7 process the same rows concurrently -> hs/x re-reads hit L2/L3.
// ---------------------------------------------------------------------------
__global__ __launch_bounds__(256) void gemm_y(
    const _Float16* __restrict__ hs, const _Float16* __restrict__ Ch,
    const float* __restrict__ x, const float* __restrict__ Dp,
    float* __restrict__ y)
{
  __shared__ _Float16 lc[128 * 256];   // 64KB, [n_local][k8p*8]

  const int tid  = threadIdx.x;
  const int lane = tid & 63;
  const int wave = tid >> 6;
  const int quad = lane >> 4;
  const int l16  = lane & 15;
  const int slab = blockIdx.x & 7;
  const int mg   = blockIdx.x >> 3;
  const int n0   = slab * 128;

  // fill C-slab once: thread t -> n = t>>1, half = t&1 (16 x 16B each)
  {
    const int n = tid >> 1, hf = tid & 1;
    const _Float16* src = Ch + (size_t)(n0 + n) * 256 + hf * 128;
    #pragma unroll
    for (int j = 0; j < 16; j++) {
      half8 v = *(const half8*)(src + j * 8);
      const int k8p = (hf * 16 + j) ^ (n & 7);
      *(half8*)&lc[n * 256 + k8p * 8] = v;
    }
  }

  // per-lane D values (columns fixed for the whole block)
  float dv[8];
  #pragma unroll
  for (int nt = 0; nt < 8; nt++) dv[nt] = Dp[n0 + nt * 16 + l16];

  __syncthreads();

  for (int i = 0; i < 8; i++) {
    const long chunk   = (long)mg * 8 + i;
    const long rowbase = chunk * 64 + wave * 16;

    // A-fragments: 8 x 16B direct from hs (f16)
    half8 af[8];
    #pragma unroll
    for (int ks = 0; ks < 8; ks++)
      af[ks] = *(const half8*)(hs + (rowbase + l16) * 256 + ks * 32 + quad * 8);

    // preload this lane's x tile (4 rows x 8 col-tiles) ahead of the MFMAs
    float xv[4][8];
    #pragma unroll
    for (int r = 0; r < 4; r++) {
      const float* gx = x + (rowbase + quad * 4 + r) * 1024 + n0 + l16;
      #pragma unroll
      for (int nt = 0; nt < 8; nt++) xv[r][nt] = gx[nt * 16];
    }

    f32x4 acc[8];
    #pragma unroll
    for (int nt = 0; nt < 8; nt++) acc[nt] = (f32x4){0.f, 0.f, 0.f, 0.f};

    #pragma unroll
    for (int ks = 0; ks < 8; ks++) {
      #pragma unroll
      for (int nt = 0; nt < 8; nt++) {
        const int n   = nt * 16 + l16;
        const int k8p = (ks * 4 + quad) ^ (n & 7);
        half8 bf = *(const half8*)&lc[n * 256 + k8p * 8];
        acc[nt] = __builtin_amdgcn_mfma_f32_16x16x32_f16(af[ks], bf, acc[nt], 0, 0, 0);
      }
    }

    // epilogue: y = acc + D*x (4 rows x 8 col-tiles per lane)
    #pragma unroll
    for (int r = 0; r < 4; r++) {
      float* gy = y + (rowbase + quad * 4 + r) * 1024 + n0 + l16;
      #pragma unroll
      for (int nt = 0; nt < 8; nt++)
        gy[nt * 16] = acc[nt][r] + dv[nt] * xv[r][nt];
    }
  }
}

// ---------------------------------------------------------------------------
extern "C" void kernel_launch(void* const* d_in, const int* in_sizes, int n_in,
                              void* d_out, int out_size, void* d_ws, size_t ws_size,
                              hipStream_t stream) {
  const float* x  = (const float*)d_in[0];
  const float* Ap = (const float*)d_in[1];
  const float* Bp = (const float*)d_in[2];
  const float* Cp = (const float*)d_in[3];
  const float* Dp = (const float*)d_in[4];
  float* y = (float*)d_out;

  // ws: Bxh 16.8MB | Bh 512KB | Ch 512KB | E 512KB | carry 512KB
  _Float16* Bxh = (_Float16*)d_ws;
  _Float16* Bh  = Bxh + (size_t)32768 * 256;
  _Float16* Ch  = Bh + (size_t)256 * 1024;
  float* E      = (float*)(Ch + (size_t)1024 * 256);
  float* carry  = E + (size_t)512 * 256;

  cvt_bc     <<<256, 256, 0, stream>>>(Bp, Cp, Bh, Ch);
  gemm_bx    <<<512, 256, 0, stream>>>(x, Bh, Bxh);
  scan_E     <<<512, 256, 0, stream>>>(Bxh, Ap, E);
  scan_prefix<<<8,   256, 0, stream>>>(E, Ap, carry);
  scan_apply <<<512, 256, 0, stream>>>(Bxh, Ap, carry);
  gemm_y     <<<512, 256, 0, stream>>>(Bxh, Ch, x, Dp, y);
}